// Round 1
// baseline (72661.194 us; speedup 1.0000x reference)
//
#include <hip/hip_runtime.h>
#include <math.h>

#define N_ITERS 200
#define POWER_ITERS 30
#define B_DIM 128
#define K_DIM 10000
#define D_DIM 1024
#define ALPHA_F 4.8828125e-6f   /* 0.01 / 2048 */

// ---------------------------------------------------------------------------
// init: W=0, Z=0, v=1, u=0, norm2[31]=0
// ---------------------------------------------------------------------------
__global__ __launch_bounds__(256) void k_init(float* __restrict__ W,
                                              float* __restrict__ Z,
                                              float* __restrict__ v,
                                              float* __restrict__ u,
                                              float* __restrict__ norm2) {
    int idx = blockIdx.x * blockDim.x + threadIdx.x;
    int stride = gridDim.x * blockDim.x;
    for (int i = idx; i < B_DIM * K_DIM; i += stride) { W[i] = 0.0f; Z[i] = 0.0f; }
    for (int i = idx; i < K_DIM; i += stride) v[i] = 1.0f;
    for (int i = idx; i < D_DIM; i += stride) u[i] = 0.0f;
    for (int i = idx; i < POWER_ITERS + 1; i += stride) norm2[i] = 0.0f;
}

// ---------------------------------------------------------------------------
// u[j] += sum_k v[k]*D[k][j]   (u must be pre-zeroed)
// grid 250 blocks x 256 threads; each block handles 40 k's
// ---------------------------------------------------------------------------
__global__ __launch_bounds__(256) void k_matvec_u(const float* __restrict__ v,
                                                  const float* __restrict__ D,
                                                  float* __restrict__ u) {
    int tid = threadIdx.x;
    int kbase = blockIdx.x * 40;
    float acc0 = 0.f, acc1 = 0.f, acc2 = 0.f, acc3 = 0.f;
    for (int k = kbase; k < kbase + 40; ++k) {
        float vk = v[k];
        const float* row = D + (size_t)k * D_DIM;
        acc0 = fmaf(vk, row[tid], acc0);
        acc1 = fmaf(vk, row[tid + 256], acc1);
        acc2 = fmaf(vk, row[tid + 512], acc2);
        acc3 = fmaf(vk, row[tid + 768], acc3);
    }
    atomicAdd(&u[tid], acc0);
    atomicAdd(&u[tid + 256], acc1);
    atomicAdd(&u[tid + 512], acc2);
    atomicAdd(&u[tid + 768], acc3);
}

// ---------------------------------------------------------------------------
// r[k] = (sum_j u[j]*D[k][j]) / n ; optionally v[k]=r ; norm2 += r*r
// one wave per k: 2500 blocks x 256 threads (4 waves)
// ---------------------------------------------------------------------------
__global__ __launch_bounds__(256) void k_matvec_v(const float* __restrict__ u,
                                                  const float* __restrict__ D,
                                                  float* __restrict__ v,
                                                  float* __restrict__ n2,
                                                  int write_v) {
    int wid = blockIdx.x * 4 + (threadIdx.x >> 6);
    int lane = threadIdx.x & 63;
    if (wid >= K_DIM) return;
    const float* row = D + (size_t)wid * D_DIM;
    float acc = 0.f;
    #pragma unroll
    for (int j = 0; j < D_DIM; j += 64) acc = fmaf(u[j + lane], row[j + lane], acc);
    #pragma unroll
    for (int off = 32; off > 0; off >>= 1) acc += __shfl_down(acc, off, 64);
    if (lane == 0) {
        float r = acc * (1.0f / 1024.0f);
        if (write_v) v[wid] = r;
        atomicAdd(n2, r * r);
    }
}

// ---------------------------------------------------------------------------
// v *= 1/(sqrt(n2)+1e-12); also zero u for next matvec_u
// ---------------------------------------------------------------------------
__global__ __launch_bounds__(256) void k_vnormalize(float* __restrict__ v,
                                                    const float* __restrict__ n2,
                                                    float* __restrict__ u) {
    int idx = blockIdx.x * blockDim.x + threadIdx.x;
    float s = 1.0f / (sqrtf(*n2) + 1e-12f);
    if (idx < K_DIM) v[idx] *= s;
    if (idx < D_DIM) u[idx] = 0.0f;
}

// L = sqrt(norm2[30]); scal[0]=step=1/L; scal[1]=thresh=step*alpha
__global__ void k_Lfinalize(const float* __restrict__ n2, float* __restrict__ scal) {
    float L = sqrtf(*n2);
    float step = 1.0f / L;
    scal[0] = step;
    scal[1] = step * ALPHA_F;
}

// ---------------------------------------------------------------------------
// U = (neg ? -Y : 0)    [128x1024]
// ---------------------------------------------------------------------------
__global__ __launch_bounds__(256) void k_initU(float* __restrict__ U,
                                               const float* __restrict__ Y,
                                               int neg) {
    int idx = blockIdx.x * blockDim.x + threadIdx.x;
    int stride = gridDim.x * blockDim.x;
    for (int i = idx; i < B_DIM * D_DIM; i += stride)
        U[i] = neg ? -Y[i] : 0.0f;
}

// ---------------------------------------------------------------------------
// U += A[128,10000] @ D[10000,1024]   split-K with fp32 atomics
// grid (16, 2, 8): x=n-tile, y=m-tile, z=splitK (chunk of 1250)
// ---------------------------------------------------------------------------
__global__ __launch_bounds__(256) void k_gemm_acc(const float* __restrict__ A,
                                                  const float* __restrict__ D,
                                                  float* __restrict__ U) {
    __shared__ float As[16][68];   // [kk][m]  (transposed for float4 reads)
    __shared__ float Bs[16][68];   // [kk][n]
    int tid = threadIdx.x;
    int n0 = blockIdx.x * 64;
    int m0 = blockIdx.y * 64;
    int k0 = blockIdx.z * 1250;
    int k1 = k0 + 1250;
    int tx = tid & 15, ty = tid >> 4;
    float acc[4][4] = {};

    for (int kt = k0; kt < k1; kt += 16) {
        {   // A tile: As[kk][r] = A[(m0+r)*K + kt+kk]
            int kk = tid & 15;
            int rb = tid >> 4;
            int kg = kt + kk;
            bool ok = (kg < k1);
            #pragma unroll
            for (int it = 0; it < 4; ++it) {
                int r = rb + it * 16;
                As[kk][r] = ok ? A[(size_t)(m0 + r) * K_DIM + kg] : 0.0f;
            }
        }
        {   // B tile: Bs[kk][c] = D[(kt+kk)*1024 + n0+c]
            int c = tid & 63;
            int kk0 = tid >> 6;
            #pragma unroll
            for (int it = 0; it < 4; ++it) {
                int kk = kk0 + it * 4;
                int kg = kt + kk;
                Bs[kk][c] = (kg < k1) ? D[(size_t)kg * D_DIM + n0 + c] : 0.0f;
            }
        }
        __syncthreads();
        #pragma unroll
        for (int kk = 0; kk < 16; ++kk) {
            float4 a = *reinterpret_cast<const float4*>(&As[kk][ty * 4]);
            float4 b = *reinterpret_cast<const float4*>(&Bs[kk][tx * 4]);
            float av[4] = {a.x, a.y, a.z, a.w};
            float bv[4] = {b.x, b.y, b.z, b.w};
            #pragma unroll
            for (int i = 0; i < 4; ++i)
                #pragma unroll
                for (int j = 0; j < 4; ++j)
                    acc[i][j] = fmaf(av[i], bv[j], acc[i][j]);
        }
        __syncthreads();
    }
    #pragma unroll
    for (int i = 0; i < 4; ++i)
        #pragma unroll
        for (int j = 0; j < 4; ++j)
            atomicAdd(&U[(size_t)(m0 + ty * 4 + i) * D_DIM + n0 + tx * 4 + j], acc[i][j]);
}

// ---------------------------------------------------------------------------
// grad = U[128,1024] @ D^T / n ; fused FISTA prox + momentum update of W,Z
// grid (157, 2): x = k-tile (64 wide, last partial), y = i-tile
// ---------------------------------------------------------------------------
__global__ __launch_bounds__(256) void k_gemm2_prox(const float* __restrict__ U,
                                                    const float* __restrict__ D,
                                                    float* __restrict__ W,
                                                    float* __restrict__ Z,
                                                    const float* __restrict__ scal,
                                                    float mom) {
    __shared__ float As[16][68];   // [jj][i]
    __shared__ float Bs[16][68];   // [jj][k]
    int tid = threadIdx.x;
    int k0 = blockIdx.x * 64;
    int i0 = blockIdx.y * 64;
    int tx = tid & 15, ty = tid >> 4;
    float acc[4][4] = {};

    for (int jt = 0; jt < D_DIM; jt += 16) {
        {   // U tile
            int jj = tid & 15;
            int rb = tid >> 4;
            #pragma unroll
            for (int it = 0; it < 4; ++it) {
                int r = rb + it * 16;
                As[jj][r] = U[(size_t)(i0 + r) * D_DIM + jt + jj];
            }
        }
        {   // D tile (rows are k; guard k<10000)
            int jj = tid & 15;
            int cb = tid >> 4;
            #pragma unroll
            for (int it = 0; it < 4; ++it) {
                int c = cb + it * 16;
                int k = k0 + c;
                Bs[jj][c] = (k < K_DIM) ? D[(size_t)k * D_DIM + jt + jj] : 0.0f;
            }
        }
        __syncthreads();
        #pragma unroll
        for (int jj = 0; jj < 16; ++jj) {
            float4 a = *reinterpret_cast<const float4*>(&As[jj][ty * 4]);
            float4 b = *reinterpret_cast<const float4*>(&Bs[jj][tx * 4]);
            float av[4] = {a.x, a.y, a.z, a.w};
            float bv[4] = {b.x, b.y, b.z, b.w};
            #pragma unroll
            for (int i = 0; i < 4; ++i)
                #pragma unroll
                for (int j = 0; j < 4; ++j)
                    acc[i][j] = fmaf(av[i], bv[j], acc[i][j]);
        }
        __syncthreads();
    }

    float step = scal[0];
    float thresh = scal[1];
    const float invN = 1.0f / 1024.0f;
    #pragma unroll
    for (int ii = 0; ii < 4; ++ii) {
        int i = i0 + ty * 4 + ii;
        #pragma unroll
        for (int jj = 0; jj < 4; ++jj) {
            int k = k0 + tx * 4 + jj;
            if (k < K_DIM) {
                size_t idx = (size_t)i * K_DIM + k;
                float g = acc[ii][jj] * invN;
                float z = Z[idx];
                float wold = W[idx];
                float wn = fmaxf(z - step * g - thresh, 0.0f);
                W[idx] = wn;
                Z[idx] = wn + mom * (wn - wold);
            }
        }
    }
}

// ---------------------------------------------------------------------------
// copy W -> out[0:1280000]; zero score slot
// ---------------------------------------------------------------------------
__global__ __launch_bounds__(256) void k_copyW(const float* __restrict__ W,
                                               float* __restrict__ out) {
    int idx = blockIdx.x * blockDim.x + threadIdx.x;
    int stride = gridDim.x * blockDim.x;
    for (int i = idx; i < B_DIM * K_DIM; i += stride) out[i] = W[i];
    if (idx == 0) out[B_DIM * K_DIM] = 0.0f;
}

// ---------------------------------------------------------------------------
// score = sum_i <recon_i, emb_i> / (||recon_i|| + 1e-12); one wave per row
// ---------------------------------------------------------------------------
__global__ __launch_bounds__(256) void k_score(const float* __restrict__ recon,
                                               const float* __restrict__ emb,
                                               float* __restrict__ score) {
    int wid = blockIdx.x * 4 + (threadIdx.x >> 6);
    int lane = threadIdx.x & 63;
    if (wid >= B_DIM) return;
    const float* r = recon + (size_t)wid * D_DIM;
    const float* e = emb + (size_t)wid * D_DIM;
    float rr = 0.f, re = 0.f;
    #pragma unroll
    for (int j = 0; j < D_DIM; j += 64) {
        float x = r[j + lane];
        rr = fmaf(x, x, rr);
        re = fmaf(x, e[j + lane], re);
    }
    #pragma unroll
    for (int off = 32; off > 0; off >>= 1) {
        rr += __shfl_down(rr, off, 64);
        re += __shfl_down(re, off, 64);
    }
    if (lane == 0) atomicAdd(score, re / (sqrtf(rr) + 1e-12f));
}

// ---------------------------------------------------------------------------
extern "C" void kernel_launch(void* const* d_in, const int* in_sizes, int n_in,
                              void* d_out, int out_size, void* d_ws, size_t ws_size,
                              hipStream_t stream) {
    const float* emb = (const float*)d_in[0];   // [128,1024]
    const float* Dm  = (const float*)d_in[1];   // [10000,1024]
    float* out = (float*)d_out;                 // 1,280,001 floats

    float* W     = (float*)d_ws;                // 1,280,000
    float* Z     = W + B_DIM * K_DIM;           // 1,280,000
    float* U     = Z + B_DIM * K_DIM;           // 131,072
    float* v     = U + B_DIM * D_DIM;           // 10,000
    float* u     = v + K_DIM;                   // 1,024
    float* norm2 = u + D_DIM;                   // 31
    float* scal  = norm2 + (POWER_ITERS + 1);   // 2

    k_init<<<512, 256, 0, stream>>>(W, Z, v, u, norm2);

    // ---- power iteration for Lipschitz constant ----
    for (int it = 0; it < POWER_ITERS; ++it) {
        k_matvec_u<<<250, 256, 0, stream>>>(v, Dm, u);
        k_matvec_v<<<2500, 256, 0, stream>>>(u, Dm, v, norm2 + it, 1);
        k_vnormalize<<<40, 256, 0, stream>>>(v, norm2 + it, u);
    }
    k_matvec_u<<<250, 256, 0, stream>>>(v, Dm, u);
    k_matvec_v<<<2500, 256, 0, stream>>>(u, Dm, nullptr, norm2 + POWER_ITERS, 0);
    k_Lfinalize<<<1, 1, 0, stream>>>(norm2 + POWER_ITERS, scal);

    // ---- FISTA ----
    double t = 1.0;
    for (int it = 0; it < N_ITERS; ++it) {
        double tn = 0.5 * (1.0 + sqrt(1.0 + 4.0 * t * t));
        float mom = (float)((t - 1.0) / tn);
        t = tn;
        k_initU<<<128, 256, 0, stream>>>(U, emb, 1);                       // U = -Y
        k_gemm_acc<<<dim3(16, 2, 8), 256, 0, stream>>>(Z, Dm, U);          // U += Z@D
        k_gemm2_prox<<<dim3(157, 2), 256, 0, stream>>>(U, Dm, W, Z, scal, mom);
    }

    // ---- epilogue: recon = W@D, normalize, score ----
    k_initU<<<128, 256, 0, stream>>>(U, emb, 0);                           // U = 0
    k_gemm_acc<<<dim3(16, 2, 8), 256, 0, stream>>>(W, Dm, U);              // U = W@D
    k_copyW<<<640, 256, 0, stream>>>(W, out);
    k_score<<<32, 256, 0, stream>>>(U, emb, out + B_DIM * K_DIM);
}

// Round 2
// 18226.952 us; speedup vs baseline: 3.9865x; 3.9865x over previous
//
#include <hip/hip_runtime.h>
#include <math.h>

#define N_ITERS 200
#define POWER_ITERS 30
#define B_DIM 128
#define K_DIM 10000
#define KP 10016            /* K padded to mult of 32 (Z cols, Dth cols) */
#define K48 10048           /* K padded to mult of 64 (Dh rows) */
#define D_DIM 1024
#define ALPHA_F 4.8828125e-6f   /* 0.01 / 2048 */

typedef unsigned short u16;
typedef __attribute__((ext_vector_type(8))) short bf16x8;
typedef __attribute__((ext_vector_type(4))) float f32x4;
#define MFMA __builtin_amdgcn_mfma_f32_16x16x32_bf16

__device__ __forceinline__ u16 f2bf(float x) {
    unsigned u = __float_as_uint(x);
    u += 0x7fff + ((u >> 16) & 1);
    return (u16)(u >> 16);
}
__device__ __forceinline__ float bf2f(u16 h) {
    return __uint_as_float(((unsigned)h) << 16);
}
__device__ __forceinline__ void split2(float x, u16& h, u16& l) {
    u16 hh = f2bf(x);
    h = hh;
    l = f2bf(x - bf2f(hh));
}

// ---------------------------------------------------------------------------
// init: W=0, Z=0 (padded), Ua=0, Ub=0, v=1, u=0, norm2=0
// ---------------------------------------------------------------------------
__global__ __launch_bounds__(256) void k_init(float* __restrict__ W,
                                              float* __restrict__ Z,
                                              float* __restrict__ Ua,
                                              float* __restrict__ Ub,
                                              float* __restrict__ v,
                                              float* __restrict__ u,
                                              float* __restrict__ norm2) {
    int idx = blockIdx.x * blockDim.x + threadIdx.x;
    int stride = gridDim.x * blockDim.x;
    for (int i = idx; i < B_DIM * KP; i += stride) { W[i] = 0.0f; Z[i] = 0.0f; }
    for (int i = idx; i < B_DIM * D_DIM; i += stride) { Ua[i] = 0.0f; Ub[i] = 0.0f; }
    for (int i = idx; i < K_DIM; i += stride) v[i] = 1.0f;
    for (int i = idx; i < D_DIM; i += stride) u[i] = 0.0f;
    for (int i = idx; i < POWER_ITERS + 1; i += stride) norm2[i] = 0.0f;
}

// ---------------------------------------------------------------------------
// Convert D fp32 [10000,1024] -> Dh/Dl bf16 [10048,1024] (pad rows zero)
//                            and Dth/Dtl bf16 [1024,10016] (transposed)
// grid (314, 32), 256 threads; 32x32 tiles
// ---------------------------------------------------------------------------
__global__ __launch_bounds__(256) void k_convertD(const float* __restrict__ D,
                                                  u16* __restrict__ Dh,
                                                  u16* __restrict__ Dl,
                                                  u16* __restrict__ Dth,
                                                  u16* __restrict__ Dtl) {
    __shared__ u16 Th[32][33], Tl[32][33];
    int tx = threadIdx.x & 31, ty = threadIdx.x >> 5;
    int k0 = blockIdx.x * 32, d0 = blockIdx.y * 32;
    #pragma unroll
    for (int r = 0; r < 4; ++r) {
        int krow = k0 + ty + r * 8;
        float val = (krow < K_DIM) ? D[(size_t)krow * D_DIM + d0 + tx] : 0.0f;
        u16 h, l; split2(val, h, l);
        Dh[(size_t)krow * D_DIM + d0 + tx] = h;
        Dl[(size_t)krow * D_DIM + d0 + tx] = l;
        Th[ty + r * 8][tx] = h;
        Tl[ty + r * 8][tx] = l;
    }
    __syncthreads();
    if (k0 < KP) {
        #pragma unroll
        for (int r = 0; r < 4; ++r) {
            int d = d0 + ty + r * 8;
            int k = k0 + tx;
            Dth[(size_t)d * KP + k] = Th[tx][ty + r * 8];
            Dtl[(size_t)d * KP + k] = Tl[tx][ty + r * 8];
        }
    }
}

// ---------------------------------------------------------------------------
// power iteration kernels (fp32, unchanged from R0)
// ---------------------------------------------------------------------------
__global__ __launch_bounds__(256) void k_matvec_u(const float* __restrict__ v,
                                                  const float* __restrict__ D,
                                                  float* __restrict__ u) {
    int tid = threadIdx.x;
    int kbase = blockIdx.x * 40;
    float acc0 = 0.f, acc1 = 0.f, acc2 = 0.f, acc3 = 0.f;
    for (int k = kbase; k < kbase + 40; ++k) {
        float vk = v[k];
        const float* row = D + (size_t)k * D_DIM;
        acc0 = fmaf(vk, row[tid], acc0);
        acc1 = fmaf(vk, row[tid + 256], acc1);
        acc2 = fmaf(vk, row[tid + 512], acc2);
        acc3 = fmaf(vk, row[tid + 768], acc3);
    }
    atomicAdd(&u[tid], acc0);
    atomicAdd(&u[tid + 256], acc1);
    atomicAdd(&u[tid + 512], acc2);
    atomicAdd(&u[tid + 768], acc3);
}

__global__ __launch_bounds__(256) void k_matvec_v(const float* __restrict__ u,
                                                  const float* __restrict__ D,
                                                  float* __restrict__ v,
                                                  float* __restrict__ n2,
                                                  int write_v) {
    int wid = blockIdx.x * 4 + (threadIdx.x >> 6);
    int lane = threadIdx.x & 63;
    if (wid >= K_DIM) return;
    const float* row = D + (size_t)wid * D_DIM;
    float acc = 0.f;
    #pragma unroll
    for (int j = 0; j < D_DIM; j += 64) acc = fmaf(u[j + lane], row[j + lane], acc);
    #pragma unroll
    for (int off = 32; off > 0; off >>= 1) acc += __shfl_down(acc, off, 64);
    if (lane == 0) {
        float r = acc * (1.0f / 1024.0f);
        if (write_v) v[wid] = r;
        atomicAdd(n2, r * r);
    }
}

__global__ __launch_bounds__(256) void k_vnormalize(float* __restrict__ v,
                                                    const float* __restrict__ n2,
                                                    float* __restrict__ u) {
    int idx = blockIdx.x * blockDim.x + threadIdx.x;
    float s = 1.0f / (sqrtf(*n2) + 1e-12f);
    if (idx < K_DIM) v[idx] *= s;
    if (idx < D_DIM) u[idx] = 0.0f;
}

__global__ void k_Lfinalize(const float* __restrict__ n2, float* __restrict__ scal) {
    float L = sqrtf(*n2);
    float step = 1.0f / L;
    scal[0] = step;
    scal[1] = step * ALPHA_F;
}

// ---------------------------------------------------------------------------
// GEMM1: U[128,1024] (+=, atomic) = A[128,KP] @ D  (B from transposed Dth/Dtl)
// Split-bf16 compensated MFMA. grid (8 n-tiles, 32 splitK chunks), 256 thr.
// A rows padded to KP with zeros; Dth cols padded with zeros -> no guards.
// ---------------------------------------------------------------------------
__global__ __launch_bounds__(256) void k_zd(const float* __restrict__ A,
                                            const u16* __restrict__ Bth,
                                            const u16* __restrict__ Btl,
                                            float* __restrict__ U) {
    __shared__ __align__(16) u16 Ah[128][40], Al[128][40], Bh[128][40], Bl[128][40];
    int t = threadIdx.x;
    int n0 = blockIdx.x * 128;
    int s0 = blockIdx.y * 10;
    int s1 = s0 + 10; if (s1 > 313) s1 = 313;
    int w = t >> 6, lane = t & 63, quad = lane >> 4, lr = lane & 15;
    int wm = (w >> 1) * 64, wn = (w & 1) * 64;
    f32x4 acc[4][4] = {};
    int srow = t >> 1;
    int scol = (t & 1) * 16;
    for (int s = s0; s < s1; ++s) {
        int kt = s * 32;
        {   // stage A (fp32 -> bf16 hi/lo)
            const float* ap = A + (size_t)srow * KP + kt + scol;
            float buf[16];
            *(float4*)&buf[0]  = *(const float4*)(ap);
            *(float4*)&buf[4]  = *(const float4*)(ap + 4);
            *(float4*)&buf[8]  = *(const float4*)(ap + 8);
            *(float4*)&buf[12] = *(const float4*)(ap + 12);
            union { u16 us[16]; int4 v[2]; } hu, lu;
            #pragma unroll
            for (int q = 0; q < 16; ++q) split2(buf[q], hu.us[q], lu.us[q]);
            *(int4*)&Ah[srow][scol]     = hu.v[0];
            *(int4*)&Ah[srow][scol + 8] = hu.v[1];
            *(int4*)&Al[srow][scol]     = lu.v[0];
            *(int4*)&Al[srow][scol + 8] = lu.v[1];
        }
        {   // stage B (bf16 copy)
            const u16* bp = Bth + (size_t)(n0 + srow) * KP + kt + scol;
            const u16* lp = Btl + (size_t)(n0 + srow) * KP + kt + scol;
            *(int4*)&Bh[srow][scol]     = *(const int4*)(bp);
            *(int4*)&Bh[srow][scol + 8] = *(const int4*)(bp + 8);
            *(int4*)&Bl[srow][scol]     = *(const int4*)(lp);
            *(int4*)&Bl[srow][scol + 8] = *(const int4*)(lp + 8);
        }
        __syncthreads();
        bf16x8 aH[4], aL[4], bH[4], bL[4];
        #pragma unroll
        for (int i = 0; i < 4; ++i) {
            aH[i] = *(const bf16x8*)&Ah[wm + i * 16 + lr][quad * 8];
            aL[i] = *(const bf16x8*)&Al[wm + i * 16 + lr][quad * 8];
            bH[i] = *(const bf16x8*)&Bh[wn + i * 16 + lr][quad * 8];
            bL[i] = *(const bf16x8*)&Bl[wn + i * 16 + lr][quad * 8];
        }
        #pragma unroll
        for (int mi = 0; mi < 4; ++mi)
            #pragma unroll
            for (int ni = 0; ni < 4; ++ni) {
                acc[mi][ni] = MFMA(aL[mi], bH[ni], acc[mi][ni], 0, 0, 0);
                acc[mi][ni] = MFMA(aH[mi], bL[ni], acc[mi][ni], 0, 0, 0);
                acc[mi][ni] = MFMA(aH[mi], bH[ni], acc[mi][ni], 0, 0, 0);
            }
        __syncthreads();
    }
    #pragma unroll
    for (int mi = 0; mi < 4; ++mi)
        #pragma unroll
        for (int ni = 0; ni < 4; ++ni) {
            int d = n0 + wn + ni * 16 + lr;
            #pragma unroll
            for (int r = 0; r < 4; ++r) {
                int i = wm + mi * 16 + quad * 4 + r;
                atomicAdd(&U[(size_t)i * D_DIM + d], acc[mi][ni][r]);
            }
        }
}

// ---------------------------------------------------------------------------
// GEMM2: acc[128,10048] = A[128,1024] @ D^T  (B from Dh/Dl, rows=concepts)
// mode 0: Rout = acc/n          (A = embedding)
// mode 1: fused FISTA prox:  g = acc/n - Rin;  W,Z update;  zero Uz
// grid (157 n-tiles, 2 m-tiles), 256 threads, block tile 64x64
// ---------------------------------------------------------------------------
__global__ __launch_bounds__(256) void k_wd(const float* __restrict__ A,
                                            const u16* __restrict__ Bhg,
                                            const u16* __restrict__ Blg,
                                            const float* Rin, float* Rout,
                                            float* __restrict__ W,
                                            float* __restrict__ Z,
                                            const float* __restrict__ scal,
                                            float mom, int mode,
                                            float* __restrict__ Uz) {
    __shared__ __align__(16) u16 Ah[64][40], Al[64][40], Bh[64][40], Bl[64][40];
    int t = threadIdx.x;
    int n0 = blockIdx.x * 64;   // concept tile
    int i0 = blockIdx.y * 64;   // batch tile
    int w = t >> 6, lane = t & 63, quad = lane >> 4, lr = lane & 15;
    int wm = (w >> 1) * 32, wn = (w & 1) * 32;
    f32x4 acc[2][2] = {};
    int srow = t >> 2;
    int scol = (t & 3) * 8;
    for (int s = 0; s < 32; ++s) {
        int kt = s * 32;
        {   // stage A (fp32 -> bf16 hi/lo)
            const float* ap = A + (size_t)(i0 + srow) * D_DIM + kt + scol;
            float buf[8];
            *(float4*)&buf[0] = *(const float4*)(ap);
            *(float4*)&buf[4] = *(const float4*)(ap + 4);
            union { u16 us[8]; int4 v; } hu, lu;
            #pragma unroll
            for (int q = 0; q < 8; ++q) split2(buf[q], hu.us[q], lu.us[q]);
            *(int4*)&Ah[srow][scol] = hu.v;
            *(int4*)&Al[srow][scol] = lu.v;
        }
        {   // stage B
            const u16* bp = Bhg + (size_t)(n0 + srow) * D_DIM + kt + scol;
            const u16* lp = Blg + (size_t)(n0 + srow) * D_DIM + kt + scol;
            *(int4*)&Bh[srow][scol] = *(const int4*)bp;
            *(int4*)&Bl[srow][scol] = *(const int4*)lp;
        }
        __syncthreads();
        bf16x8 aH[2], aL[2], bH[2], bL[2];
        #pragma unroll
        for (int i = 0; i < 2; ++i) {
            aH[i] = *(const bf16x8*)&Ah[wm + i * 16 + lr][quad * 8];
            aL[i] = *(const bf16x8*)&Al[wm + i * 16 + lr][quad * 8];
            bH[i] = *(const bf16x8*)&Bh[wn + i * 16 + lr][quad * 8];
            bL[i] = *(const bf16x8*)&Bl[wn + i * 16 + lr][quad * 8];
        }
        #pragma unroll
        for (int mi = 0; mi < 2; ++mi)
            #pragma unroll
            for (int ni = 0; ni < 2; ++ni) {
                acc[mi][ni] = MFMA(aL[mi], bH[ni], acc[mi][ni], 0, 0, 0);
                acc[mi][ni] = MFMA(aH[mi], bL[ni], acc[mi][ni], 0, 0, 0);
                acc[mi][ni] = MFMA(aH[mi], bH[ni], acc[mi][ni], 0, 0, 0);
            }
        __syncthreads();
    }
    const float invN = 1.0f / 1024.0f;
    if (mode == 0) {
        #pragma unroll
        for (int mi = 0; mi < 2; ++mi)
            #pragma unroll
            for (int ni = 0; ni < 2; ++ni) {
                int k = n0 + wn + ni * 16 + lr;
                if (k < K_DIM) {
                    #pragma unroll
                    for (int r = 0; r < 4; ++r) {
                        int i = i0 + wm + mi * 16 + quad * 4 + r;
                        Rout[(size_t)i * K_DIM + k] = acc[mi][ni][r] * invN;
                    }
                }
            }
    } else {
        float step = scal[0], thresh = scal[1];
        #pragma unroll
        for (int mi = 0; mi < 2; ++mi)
            #pragma unroll
            for (int ni = 0; ni < 2; ++ni) {
                int k = n0 + wn + ni * 16 + lr;
                if (k < K_DIM) {
                    #pragma unroll
                    for (int r = 0; r < 4; ++r) {
                        int i = i0 + wm + mi * 16 + quad * 4 + r;
                        float g = acc[mi][ni][r] * invN - Rin[(size_t)i * K_DIM + k];
                        size_t idx = (size_t)i * KP + k;
                        float z = Z[idx];
                        float wold = W[idx];
                        float wnew = fmaxf(z - step * g - thresh, 0.0f);
                        W[idx] = wnew;
                        Z[idx] = wnew + mom * (wnew - wold);
                    }
                }
            }
    }
    if (Uz) {   // zero the OTHER U buffer for the next iteration's GEMM1
        int nb = gridDim.x * gridDim.y;
        int bid = blockIdx.y * gridDim.x + blockIdx.x;
        for (int idx = bid * 256 + t; idx < B_DIM * D_DIM; idx += nb * 256)
            Uz[idx] = 0.0f;
    }
}

// ---------------------------------------------------------------------------
// copy W (padded) -> out; zero score slot
// ---------------------------------------------------------------------------
__global__ __launch_bounds__(256) void k_copyW(const float* __restrict__ W,
                                               float* __restrict__ out) {
    int i = blockIdx.y;
    int k = blockIdx.x * 256 + threadIdx.x;
    if (k < K_DIM) out[(size_t)i * K_DIM + k] = W[(size_t)i * KP + k];
    if (blockIdx.x == 0 && blockIdx.y == 0 && threadIdx.x == 0)
        out[(size_t)B_DIM * K_DIM] = 0.0f;
}

// ---------------------------------------------------------------------------
// score = sum_i <recon_i, emb_i> / (||recon_i|| + 1e-12); one wave per row
// ---------------------------------------------------------------------------
__global__ __launch_bounds__(256) void k_score(const float* __restrict__ recon,
                                               const float* __restrict__ emb,
                                               float* __restrict__ score) {
    int wid = blockIdx.x * 4 + (threadIdx.x >> 6);
    int lane = threadIdx.x & 63;
    if (wid >= B_DIM) return;
    const float* r = recon + (size_t)wid * D_DIM;
    const float* e = emb + (size_t)wid * D_DIM;
    float rr = 0.f, re = 0.f;
    #pragma unroll
    for (int j = 0; j < D_DIM; j += 64) {
        float x = r[j + lane];
        rr = fmaf(x, x, rr);
        re = fmaf(x, e[j + lane], re);
    }
    #pragma unroll
    for (int off = 32; off > 0; off >>= 1) {
        rr += __shfl_down(rr, off, 64);
        re += __shfl_down(re, off, 64);
    }
    if (lane == 0) atomicAdd(score, re / (sqrtf(rr) + 1e-12f));
}

// ---------------------------------------------------------------------------
extern "C" void kernel_launch(void* const* d_in, const int* in_sizes, int n_in,
                              void* d_out, int out_size, void* d_ws, size_t ws_size,
                              hipStream_t stream) {
    const float* emb = (const float*)d_in[0];   // [128,1024]
    const float* Dm  = (const float*)d_in[1];   // [10000,1024]
    float* out = (float*)d_out;

    size_t off = 0;
    auto carve = [&](size_t bytes) -> void* {
        void* r = (char*)d_ws + off;
        off += (bytes + 255) & ~(size_t)255;
        return r;
    };
    float* W     = (float*)carve((size_t)B_DIM * KP * 4);
    float* Z     = (float*)carve((size_t)B_DIM * KP * 4);
    float* R     = (float*)carve((size_t)B_DIM * K_DIM * 4);
    float* Ua    = (float*)carve((size_t)B_DIM * D_DIM * 4);
    float* Ub    = (float*)carve((size_t)B_DIM * D_DIM * 4);
    float* v     = (float*)carve(K_DIM * 4);
    float* u     = (float*)carve(D_DIM * 4);
    float* norm2 = (float*)carve((POWER_ITERS + 1) * 4);
    float* scal  = (float*)carve(2 * 4);
    u16* Dh  = (u16*)carve((size_t)K48 * D_DIM * 2);
    u16* Dl  = (u16*)carve((size_t)K48 * D_DIM * 2);
    u16* Dth = (u16*)carve((size_t)D_DIM * KP * 2);
    u16* Dtl = (u16*)carve((size_t)D_DIM * KP * 2);

    k_init<<<512, 256, 0, stream>>>(W, Z, Ua, Ub, v, u, norm2);
    k_convertD<<<dim3(314, 32), 256, 0, stream>>>(Dm, Dh, Dl, Dth, Dtl);

    // ---- power iteration for Lipschitz constant (fp32) ----
    for (int it = 0; it < POWER_ITERS; ++it) {
        k_matvec_u<<<250, 256, 0, stream>>>(v, Dm, u);
        k_matvec_v<<<2500, 256, 0, stream>>>(u, Dm, v, norm2 + it, 1);
        k_vnormalize<<<40, 256, 0, stream>>>(v, norm2 + it, u);
    }
    k_matvec_u<<<250, 256, 0, stream>>>(v, Dm, u);
    k_matvec_v<<<2500, 256, 0, stream>>>(u, Dm, nullptr, norm2 + POWER_ITERS, 0);
    k_Lfinalize<<<1, 1, 0, stream>>>(norm2 + POWER_ITERS, scal);

    // ---- R = Y @ D^T / n  (mode 0) ----
    k_wd<<<dim3(157, 2), 256, 0, stream>>>(emb, Dh, Dl, nullptr, R,
                                           nullptr, nullptr, scal, 0.0f, 0, nullptr);

    // ---- FISTA ----
    double t = 1.0;
    for (int it = 0; it < N_ITERS; ++it) {
        double tn = 0.5 * (1.0 + sqrt(1.0 + 4.0 * t * t));
        float mom = (float)((t - 1.0) / tn);
        t = tn;
        float* Ucur  = (it & 1) ? Ub : Ua;
        float* Unext = (it & 1) ? Ua : Ub;
        k_zd<<<dim3(8, 32), 256, 0, stream>>>(Z, Dth, Dtl, Ucur);
        k_wd<<<dim3(157, 2), 256, 0, stream>>>(Ucur, Dh, Dl, R, nullptr,
                                               W, Z, scal, mom, 1, Unext);
    }

    // ---- epilogue: recon = W@D (into Ua, zeroed by last k_wd), score ----
    k_zd<<<dim3(8, 32), 256, 0, stream>>>(W, Dth, Dtl, Ua);
    k_copyW<<<dim3(40, 128), 256, 0, stream>>>(W, out);
    k_score<<<32, 256, 0, stream>>>(Ua, emb, out + (size_t)B_DIM * K_DIM);
}

// Round 3
// 17403.935 us; speedup vs baseline: 4.1750x; 1.0473x over previous
//
#include <hip/hip_runtime.h>
#include <math.h>

#define N_ITERS 200
#define POWER_ITERS 30
#define B_DIM 128
#define K_DIM 10000
#define KP 10016            /* K padded to mult of 32 */
#define K48 10048           /* K padded to mult of 64 */
#define D_DIM 1024
#define ALPHA_F 4.8828125e-6f   /* 0.01 / 2048 */
#define SPLITK 10
#define CHUNK 31            /* k-steps per split; last split gets 313-9*31=34 */
#define NSTEPS 313          /* KP/32 */

typedef unsigned short u16;
typedef __attribute__((ext_vector_type(8))) short bf16x8;
typedef __attribute__((ext_vector_type(4))) float f32x4;
#define MFMA __builtin_amdgcn_mfma_f32_16x16x32_bf16

__device__ __forceinline__ u16 f2bf(float x) {
    unsigned u = __float_as_uint(x);
    u += 0x7fff + ((u >> 16) & 1);
    return (u16)(u >> 16);
}
__device__ __forceinline__ float bf2f(u16 h) {
    return __uint_as_float(((unsigned)h) << 16);
}
__device__ __forceinline__ void split2(float x, u16& h, u16& l) {
    u16 hh = f2bf(x);
    h = hh;
    l = f2bf(x - bf2f(hh));
}
// LDS chunk swizzle: row r (64B = 4 chunks of 16B), logical chunk q stored at
// slot q ^ swz(r). Gives uniform 16B-unit distribution for stride-64B b128 frag
// reads (8 distinct units over any 8 consecutive rows).
__device__ __forceinline__ int swz(int r) { return (r & 3) ^ ((r >> 2) & 1); }

// ---------------------------------------------------------------------------
// init: W(=d_out)=0, score=0, Zh/Zl=0, split emb -> Eh/El (aliased Uh/Ul),
//       v=1, u=0, norm2=0
// ---------------------------------------------------------------------------
__global__ __launch_bounds__(256) void k_init(float* __restrict__ out,
                                              u16* __restrict__ Zh, u16* __restrict__ Zl,
                                              const float* __restrict__ emb,
                                              u16* __restrict__ Eh, u16* __restrict__ El,
                                              float* __restrict__ v, float* __restrict__ u,
                                              float* __restrict__ norm2) {
    int idx = blockIdx.x * 256 + threadIdx.x;
    int stride = gridDim.x * 256;
    for (int i = idx; i <= B_DIM * K_DIM; i += stride) out[i] = 0.0f;
    unsigned* zh = (unsigned*)Zh;
    unsigned* zl = (unsigned*)Zl;
    for (int i = idx; i < B_DIM * KP / 2; i += stride) { zh[i] = 0u; zl[i] = 0u; }
    for (int i = idx; i < B_DIM * D_DIM; i += stride) {
        u16 h, l; split2(emb[i], h, l);
        Eh[i] = h; El[i] = l;
    }
    for (int i = idx; i < K_DIM; i += stride) v[i] = 1.0f;
    for (int i = idx; i < D_DIM; i += stride) u[i] = 0.0f;
    for (int i = idx; i < POWER_ITERS + 1; i += stride) norm2[i] = 0.0f;
}

// ---------------------------------------------------------------------------
// Convert D fp32 [10000,1024] -> Dh/Dl bf16 [10048,1024] (pad rows zero)
//                            and Dth/Dtl bf16 [1024,10016] (transposed)
// ---------------------------------------------------------------------------
__global__ __launch_bounds__(256) void k_convertD(const float* __restrict__ D,
                                                  u16* __restrict__ Dh,
                                                  u16* __restrict__ Dl,
                                                  u16* __restrict__ Dth,
                                                  u16* __restrict__ Dtl) {
    __shared__ u16 Th[32][33], Tl[32][33];
    int tx = threadIdx.x & 31, ty = threadIdx.x >> 5;
    int k0 = blockIdx.x * 32, d0 = blockIdx.y * 32;
    #pragma unroll
    for (int r = 0; r < 4; ++r) {
        int krow = k0 + ty + r * 8;
        float val = (krow < K_DIM) ? D[(size_t)krow * D_DIM + d0 + tx] : 0.0f;
        u16 h, l; split2(val, h, l);
        Dh[(size_t)krow * D_DIM + d0 + tx] = h;
        Dl[(size_t)krow * D_DIM + d0 + tx] = l;
        Th[ty + r * 8][tx] = h;
        Tl[ty + r * 8][tx] = l;
    }
    __syncthreads();
    if (k0 < KP) {
        #pragma unroll
        for (int r = 0; r < 4; ++r) {
            int d = d0 + ty + r * 8;
            int k = k0 + tx;
            Dth[(size_t)d * KP + k] = Th[tx][ty + r * 8];
            Dtl[(size_t)d * KP + k] = Tl[tx][ty + r * 8];
        }
    }
}

// ---------------------------------------------------------------------------
// power iteration kernels (fp32)
// ---------------------------------------------------------------------------
__global__ __launch_bounds__(256) void k_matvec_u(const float* __restrict__ v,
                                                  const float* __restrict__ D,
                                                  float* __restrict__ u) {
    int tid = threadIdx.x;
    int kbase = blockIdx.x * 40;
    float acc0 = 0.f, acc1 = 0.f, acc2 = 0.f, acc3 = 0.f;
    for (int k = kbase; k < kbase + 40; ++k) {
        float vk = v[k];
        const float* row = D + (size_t)k * D_DIM;
        acc0 = fmaf(vk, row[tid], acc0);
        acc1 = fmaf(vk, row[tid + 256], acc1);
        acc2 = fmaf(vk, row[tid + 512], acc2);
        acc3 = fmaf(vk, row[tid + 768], acc3);
    }
    atomicAdd(&u[tid], acc0);
    atomicAdd(&u[tid + 256], acc1);
    atomicAdd(&u[tid + 512], acc2);
    atomicAdd(&u[tid + 768], acc3);
}

__global__ __launch_bounds__(256) void k_matvec_v(const float* __restrict__ u,
                                                  const float* __restrict__ D,
                                                  float* __restrict__ v,
                                                  float* __restrict__ n2,
                                                  int write_v) {
    int wid = blockIdx.x * 4 + (threadIdx.x >> 6);
    int lane = threadIdx.x & 63;
    if (wid >= K_DIM) return;
    const float* row = D + (size_t)wid * D_DIM;
    float acc = 0.f;
    #pragma unroll
    for (int j = 0; j < D_DIM; j += 64) acc = fmaf(u[j + lane], row[j + lane], acc);
    #pragma unroll
    for (int off = 32; off > 0; off >>= 1) acc += __shfl_down(acc, off, 64);
    if (lane == 0) {
        float r = acc * (1.0f / 1024.0f);
        if (write_v) v[wid] = r;
        atomicAdd(n2, r * r);
    }
}

__global__ __launch_bounds__(256) void k_vnormalize(float* __restrict__ v,
                                                    const float* __restrict__ n2,
                                                    float* __restrict__ u) {
    int idx = blockIdx.x * blockDim.x + threadIdx.x;
    float s = 1.0f / (sqrtf(*n2) + 1e-12f);
    if (idx < K_DIM) v[idx] *= s;
    if (idx < D_DIM) u[idx] = 0.0f;
}

__global__ void k_Lfinalize(const float* __restrict__ n2, float* __restrict__ scal) {
    float L = sqrtf(*n2);
    float step = 1.0f / L;
    scal[0] = step;
    scal[1] = step * ALPHA_F;
}

// ---------------------------------------------------------------------------
// kA: Up[split][128][1024] = chunk of A[128,KP] @ Dth^T  (both K-major bf16,
// split-compensated). grid (16 n-tiles of 64, SPLITK), 256 thr, tile 128x64.
// ---------------------------------------------------------------------------
__global__ __launch_bounds__(256) void k_gemm1(const u16* __restrict__ Azh,
                                               const u16* __restrict__ Azl,
                                               const u16* __restrict__ Bth,
                                               const u16* __restrict__ Btl,
                                               float* __restrict__ Up) {
    __shared__ __align__(16) u16 lds[12288];
    u16* Ah = lds;            // [128][32]
    u16* Al = lds + 4096;
    u16* Bh = lds + 8192;     // [64][32]
    u16* Bl = lds + 10240;
    int t = threadIdx.x;
    int n0 = blockIdx.x * 64;
    int split = blockIdx.y;
    int s0 = split * CHUNK;
    int s1 = (split == SPLITK - 1) ? NSTEPS : (s0 + CHUNK);
    int w = t >> 6, lane = t & 63, quad = lane >> 4, lr = lane & 15;
    int wm = (w >> 1) * 64, wn = (w & 1) * 32;

    int r0 = t >> 2, qs = t & 3;
    int qA0 = qs ^ swz(r0), qA1 = qs ^ swz(r0 + 64);
    const u16* pA0h = Azh + (size_t)r0 * KP + s0 * 32 + qA0 * 8;
    const u16* pA1h = Azh + (size_t)(r0 + 64) * KP + s0 * 32 + qA1 * 8;
    const u16* pA0l = Azl + (size_t)r0 * KP + s0 * 32 + qA0 * 8;
    const u16* pA1l = Azl + (size_t)(r0 + 64) * KP + s0 * 32 + qA1 * 8;
    const u16* pBh  = Bth + (size_t)(n0 + r0) * KP + s0 * 32 + qA0 * 8;
    const u16* pBl  = Btl + (size_t)(n0 + r0) * KP + s0 * 32 + qA0 * 8;
    u16* dA0h = &Ah[r0 * 32 + qs * 8];
    u16* dA1h = &Ah[(r0 + 64) * 32 + qs * 8];
    u16* dA0l = &Al[r0 * 32 + qs * 8];
    u16* dA1l = &Al[(r0 + 64) * 32 + qs * 8];
    u16* dBh  = &Bh[r0 * 32 + qs * 8];
    u16* dBl  = &Bl[r0 * 32 + qs * 8];

    int offA[4], offB[2];
    #pragma unroll
    for (int mi = 0; mi < 4; ++mi) { int rr = wm + mi * 16 + lr; offA[mi] = rr * 32 + ((quad ^ swz(rr)) * 8); }
    #pragma unroll
    for (int ni = 0; ni < 2; ++ni) { int rr = wn + ni * 16 + lr; offB[ni] = rr * 32 + ((quad ^ swz(rr)) * 8); }

    f32x4 acc[4][2] = {};
    int4 b0, b1, b2, b3, b4, b5;
    b0 = *(const int4*)pA0h; b1 = *(const int4*)pA1h; b2 = *(const int4*)pA0l;
    b3 = *(const int4*)pA1l; b4 = *(const int4*)pBh;  b5 = *(const int4*)pBl;

    for (int s = s0; s < s1; ++s) {
        *(int4*)dA0h = b0; *(int4*)dA1h = b1; *(int4*)dA0l = b2;
        *(int4*)dA1l = b3; *(int4*)dBh  = b4; *(int4*)dBl  = b5;
        __syncthreads();
        pA0h += 32; pA1h += 32; pA0l += 32; pA1l += 32; pBh += 32; pBl += 32;
        if (s + 1 < s1) {
            b0 = *(const int4*)pA0h; b1 = *(const int4*)pA1h; b2 = *(const int4*)pA0l;
            b3 = *(const int4*)pA1l; b4 = *(const int4*)pBh;  b5 = *(const int4*)pBl;
        }
        bf16x8 aH[4], aL[4], bH[2], bL[2];
        #pragma unroll
        for (int mi = 0; mi < 4; ++mi) { aH[mi] = *(const bf16x8*)&Ah[offA[mi]]; aL[mi] = *(const bf16x8*)&Al[offA[mi]]; }
        #pragma unroll
        for (int ni = 0; ni < 2; ++ni) { bH[ni] = *(const bf16x8*)&Bh[offB[ni]]; bL[ni] = *(const bf16x8*)&Bl[offB[ni]]; }
        #pragma unroll
        for (int mi = 0; mi < 4; ++mi)
            #pragma unroll
            for (int ni = 0; ni < 2; ++ni) {
                acc[mi][ni] = MFMA(aL[mi], bH[ni], acc[mi][ni], 0, 0, 0);
                acc[mi][ni] = MFMA(aH[mi], bL[ni], acc[mi][ni], 0, 0, 0);
                acc[mi][ni] = MFMA(aH[mi], bH[ni], acc[mi][ni], 0, 0, 0);
            }
        __syncthreads();
    }
    float* base = Up + (size_t)split * (B_DIM * D_DIM);
    #pragma unroll
    for (int mi = 0; mi < 4; ++mi)
        #pragma unroll
        for (int ni = 0; ni < 2; ++ni) {
            int d = n0 + wn + ni * 16 + lr;
            #pragma unroll
            for (int r = 0; r < 4; ++r) {
                int i = wm + mi * 16 + quad * 4 + r;
                base[(size_t)i * D_DIM + d] = acc[mi][ni][r];
            }
        }
}

// ---------------------------------------------------------------------------
// kB: Uh/Ul = split( sum over SPLITK partials )
// ---------------------------------------------------------------------------
__global__ __launch_bounds__(256) void k_reduceU(const float* __restrict__ Up,
                                                 u16* __restrict__ Uh,
                                                 u16* __restrict__ Ul) {
    int base = (blockIdx.x * 256 + threadIdx.x) * 8;    // grid 64 -> 131072 elems
    float4 s0 = {0, 0, 0, 0}, s1 = {0, 0, 0, 0};
    #pragma unroll
    for (int s = 0; s < SPLITK; ++s) {
        const float* p = Up + (size_t)s * (B_DIM * D_DIM) + base;
        float4 a = *(const float4*)p;
        float4 b = *(const float4*)(p + 4);
        s0.x += a.x; s0.y += a.y; s0.z += a.z; s0.w += a.w;
        s1.x += b.x; s1.y += b.y; s1.z += b.z; s1.w += b.w;
    }
    float vbuf[8] = {s0.x, s0.y, s0.z, s0.w, s1.x, s1.y, s1.z, s1.w};
    union { u16 us[8]; int4 v; } h, l;
    #pragma unroll
    for (int q = 0; q < 8; ++q) split2(vbuf[q], h.us[q], l.us[q]);
    *(int4*)&Uh[base] = h.v;
    *(int4*)&Ul[base] = l.v;
}

// ---------------------------------------------------------------------------
// kC: acc[128,10048] = A[128,1024] @ Dh^T (both K-major bf16, compensated).
// mode 0: R = acc/n (A = split emb)
// mode 1: fused FISTA prox; writes W (fp32, in d_out) and Zh/Zl (split z_new);
//         writeW=1 (last iter): Zh/Zl get split(w_new) instead, for recon pass.
// grid (157 n-tiles of 64, 2 m-tiles of 64), 256 thr.
// ---------------------------------------------------------------------------
__global__ __launch_bounds__(256) void k_gemm2(const u16* __restrict__ Ahg,
                                               const u16* __restrict__ Alg,
                                               const u16* __restrict__ Bhg,
                                               const u16* __restrict__ Blg,
                                               float* __restrict__ R,
                                               float* __restrict__ W,
                                               u16* __restrict__ Zh, u16* __restrict__ Zl,
                                               const float* __restrict__ scal,
                                               float mom, int mode, int writeW) {
    __shared__ __align__(16) u16 lds[8192];
    u16* Ah = lds;            // [64][32]
    u16* Al = lds + 2048;
    u16* Bh = lds + 4096;
    u16* Bl = lds + 6144;
    int t = threadIdx.x;
    int n0 = blockIdx.x * 64;
    int i0 = blockIdx.y * 64;
    int w = t >> 6, lane = t & 63, quad = lane >> 4, lr = lane & 15;
    int wm = (w >> 1) * 32, wn = (w & 1) * 32;

    int r0 = t >> 2, qs = t & 3, q = qs ^ swz(r0);
    const u16* pAh = Ahg + (size_t)(i0 + r0) * D_DIM + q * 8;
    const u16* pAl = Alg + (size_t)(i0 + r0) * D_DIM + q * 8;
    const u16* pBh = Bhg + (size_t)(n0 + r0) * D_DIM + q * 8;
    const u16* pBl = Blg + (size_t)(n0 + r0) * D_DIM + q * 8;
    u16* dAh = &Ah[r0 * 32 + qs * 8];
    u16* dAl = &Al[r0 * 32 + qs * 8];
    u16* dBh = &Bh[r0 * 32 + qs * 8];
    u16* dBl = &Bl[r0 * 32 + qs * 8];

    int offA[2], offB[2];
    #pragma unroll
    for (int mi = 0; mi < 2; ++mi) { int rr = wm + mi * 16 + lr; offA[mi] = rr * 32 + ((quad ^ swz(rr)) * 8); }
    #pragma unroll
    for (int ni = 0; ni < 2; ++ni) { int rr = wn + ni * 16 + lr; offB[ni] = rr * 32 + ((quad ^ swz(rr)) * 8); }

    f32x4 acc[2][2] = {};
    int4 b0, b1, b2, b3;
    b0 = *(const int4*)pAh; b1 = *(const int4*)pAl;
    b2 = *(const int4*)pBh; b3 = *(const int4*)pBl;

    for (int s = 0; s < 32; ++s) {
        *(int4*)dAh = b0; *(int4*)dAl = b1;
        *(int4*)dBh = b2; *(int4*)dBl = b3;
        __syncthreads();
        pAh += 32; pAl += 32; pBh += 32; pBl += 32;
        if (s + 1 < 32) {
            b0 = *(const int4*)pAh; b1 = *(const int4*)pAl;
            b2 = *(const int4*)pBh; b3 = *(const int4*)pBl;
        }
        bf16x8 aH[2], aL[2], bH[2], bL[2];
        #pragma unroll
        for (int mi = 0; mi < 2; ++mi) { aH[mi] = *(const bf16x8*)&Ah[offA[mi]]; aL[mi] = *(const bf16x8*)&Al[offA[mi]]; }
        #pragma unroll
        for (int ni = 0; ni < 2; ++ni) { bH[ni] = *(const bf16x8*)&Bh[offB[ni]]; bL[ni] = *(const bf16x8*)&Bl[offB[ni]]; }
        #pragma unroll
        for (int mi = 0; mi < 2; ++mi)
            #pragma unroll
            for (int ni = 0; ni < 2; ++ni) {
                acc[mi][ni] = MFMA(aL[mi], bH[ni], acc[mi][ni], 0, 0, 0);
                acc[mi][ni] = MFMA(aH[mi], bL[ni], acc[mi][ni], 0, 0, 0);
                acc[mi][ni] = MFMA(aH[mi], bH[ni], acc[mi][ni], 0, 0, 0);
            }
        __syncthreads();
    }

    const float invN = 1.0f / 1024.0f;
    if (mode == 0) {
        #pragma unroll
        for (int ni = 0; ni < 2; ++ni) {
            int k = n0 + wn + ni * 16 + lr;
            if (k < K_DIM) {
                #pragma unroll
                for (int mi = 0; mi < 2; ++mi)
                    #pragma unroll
                    for (int r = 0; r < 4; ++r) {
                        int i = i0 + wm + mi * 16 + quad * 4 + r;
                        R[(size_t)i * K_DIM + k] = acc[mi][ni][r] * invN;
                    }
            }
        }
    } else {
        float step = scal[0], th = scal[1];
        #pragma unroll
        for (int ni = 0; ni < 2; ++ni) {
            int k = n0 + wn + ni * 16 + lr;
            if (k < K_DIM) {
                #pragma unroll
                for (int mi = 0; mi < 2; ++mi)
                    #pragma unroll
                    for (int r = 0; r < 4; ++r) {
                        int i = i0 + wm + mi * 16 + quad * 4 + r;
                        size_t ik = (size_t)i * K_DIM + k;
                        size_t iz = (size_t)i * KP + k;
                        float g = acc[mi][ni][r] * invN - R[ik];
                        float z = bf2f(Zh[iz]) + bf2f(Zl[iz]);
                        float wold = W[ik];
                        float wnew = fmaxf(z - step * g - th, 0.0f);
                        float zn = wnew + mom * (wnew - wold);
                        W[ik] = wnew;
                        u16 h, l;
                        if (writeW) split2(wnew, h, l);
                        else        split2(zn, h, l);
                        Zh[iz] = h;
                        Zl[iz] = l;
                    }
            }
        }
    }
}

// ---------------------------------------------------------------------------
// score = sum_i <recon_i, emb_i> / (||recon_i|| + 1e-12); recon from split U
// ---------------------------------------------------------------------------
__global__ __launch_bounds__(256) void k_score(const u16* __restrict__ Uh,
                                               const u16* __restrict__ Ul,
                                               const float* __restrict__ emb,
                                               float* __restrict__ score) {
    int wid = blockIdx.x * 4 + (threadIdx.x >> 6);
    int lane = threadIdx.x & 63;
    if (wid >= B_DIM) return;
    float rr = 0.f, re = 0.f;
    #pragma unroll
    for (int j = 0; j < D_DIM; j += 64) {
        int idx = wid * D_DIM + j + lane;
        float x = bf2f(Uh[idx]) + bf2f(Ul[idx]);
        rr = fmaf(x, x, rr);
        re = fmaf(x, emb[idx], re);
    }
    #pragma unroll
    for (int off = 32; off > 0; off >>= 1) {
        rr += __shfl_down(rr, off, 64);
        re += __shfl_down(re, off, 64);
    }
    if (lane == 0) atomicAdd(score, re / (sqrtf(rr) + 1e-12f));
}

// ---------------------------------------------------------------------------
extern "C" void kernel_launch(void* const* d_in, const int* in_sizes, int n_in,
                              void* d_out, int out_size, void* d_ws, size_t ws_size,
                              hipStream_t stream) {
    const float* emb = (const float*)d_in[0];   // [128,1024]
    const float* Dm  = (const float*)d_in[1];   // [10000,1024]
    float* out = (float*)d_out;
    float* W = out;                             // W lives in d_out [128][10000]

    size_t off = 0;
    auto carve = [&](size_t bytes) -> void* {
        void* r = (char*)d_ws + off;
        off += (bytes + 255) & ~(size_t)255;
        return r;
    };
    float* R     = (float*)carve((size_t)B_DIM * K_DIM * 4);            // 5.12 MB
    float* Up    = (float*)carve((size_t)SPLITK * B_DIM * D_DIM * 4);   // 5.24 MB
    u16*   Zh    = (u16*)carve((size_t)B_DIM * KP * 2);                 // 2.56 MB
    u16*   Zl    = (u16*)carve((size_t)B_DIM * KP * 2);
    u16*   Uh    = (u16*)carve((size_t)B_DIM * D_DIM * 2);              // 0.26 MB
    u16*   Ul    = (u16*)carve((size_t)B_DIM * D_DIM * 2);
    float* v     = (float*)carve(K_DIM * 4);
    float* u     = (float*)carve(D_DIM * 4);
    float* norm2 = (float*)carve((POWER_ITERS + 1) * 4);
    float* scal  = (float*)carve(2 * 4);
    u16* Dh  = (u16*)carve((size_t)K48 * D_DIM * 2);                    // 20.6 MB
    u16* Dl  = (u16*)carve((size_t)K48 * D_DIM * 2);
    u16* Dth = (u16*)carve((size_t)D_DIM * KP * 2);                     // 20.5 MB
    u16* Dtl = (u16*)carve((size_t)D_DIM * KP * 2);

    k_init<<<512, 256, 0, stream>>>(out, Zh, Zl, emb, Uh, Ul, v, u, norm2);
    k_convertD<<<dim3(314, 32), 256, 0, stream>>>(Dm, Dh, Dl, Dth, Dtl);

    // ---- power iteration for Lipschitz constant (fp32) ----
    for (int it = 0; it < POWER_ITERS; ++it) {
        k_matvec_u<<<250, 256, 0, stream>>>(v, Dm, u);
        k_matvec_v<<<2500, 256, 0, stream>>>(u, Dm, v, norm2 + it, 1);
        k_vnormalize<<<40, 256, 0, stream>>>(v, norm2 + it, u);
    }
    k_matvec_u<<<250, 256, 0, stream>>>(v, Dm, u);
    k_matvec_v<<<2500, 256, 0, stream>>>(u, Dm, nullptr, norm2 + POWER_ITERS, 0);
    k_Lfinalize<<<1, 1, 0, stream>>>(norm2 + POWER_ITERS, scal);

    // ---- R = Y @ D^T / n (mode 0; A = split emb, staged in Uh/Ul by k_init) ----
    k_gemm2<<<dim3(157, 2), 256, 0, stream>>>(Uh, Ul, Dh, Dl, R, W, Zh, Zl,
                                              scal, 0.0f, 0, 0);

    // ---- FISTA ----
    double t = 1.0;
    for (int it = 0; it < N_ITERS; ++it) {
        double tn = 0.5 * (1.0 + sqrt(1.0 + 4.0 * t * t));
        float mom = (float)((t - 1.0) / tn);
        t = tn;
        k_gemm1<<<dim3(16, SPLITK), 256, 0, stream>>>(Zh, Zl, Dth, Dtl, Up);
        k_reduceU<<<64, 256, 0, stream>>>(Up, Uh, Ul);
        k_gemm2<<<dim3(157, 2), 256, 0, stream>>>(Uh, Ul, Dh, Dl, R, W, Zh, Zl,
                                                  scal, mom, 1,
                                                  (it == N_ITERS - 1) ? 1 : 0);
    }

    // ---- epilogue: recon = W@D (Zh/Zl hold split W after last iter) ----
    k_gemm1<<<dim3(16, SPLITK), 256, 0, stream>>>(Zh, Zl, Dth, Dtl, Up);
    k_reduceU<<<64, 256, 0, stream>>>(Up, Uh, Ul);
    k_score<<<32, 256, 0, stream>>>(Uh, Ul, emb, out + (size_t)B_DIM * K_DIM);
}

// Round 4
// 15134.709 us; speedup vs baseline: 4.8010x; 1.1499x over previous
//
#include <hip/hip_runtime.h>
#include <math.h>

#define N_ITERS 200
#define POWER_ITERS 30
#define B_DIM 128
#define K_DIM 10000
#define KP2 10240           /* Z cols / Dth cols: 10 ksplits x 1024 */
#define KB  10048           /* Dh rows / R stride (157 tiles x 64) */
#define D_DIM 1024
#define ALPHA_F 4.8828125e-6f   /* 0.01 / 2048 */
#define SPLITK 10

typedef unsigned short u16;
typedef __attribute__((ext_vector_type(8))) short bf16x8;
typedef __attribute__((ext_vector_type(4))) float f32x4;
#define MFMA __builtin_amdgcn_mfma_f32_16x16x32_bf16

__device__ __forceinline__ u16 f2bf(float x) {
    unsigned u = __float_as_uint(x);
    u += 0x7fff + ((u >> 16) & 1);
    return (u16)(u >> 16);
}
__device__ __forceinline__ float bf2f(u16 h) {
    return __uint_as_float(((unsigned)h) << 16);
}
__device__ __forceinline__ void split2(float x, u16& h, u16& l) {
    u16 hh = f2bf(x);
    h = hh;
    l = f2bf(x - bf2f(hh));
}
// LDS 16B-chunk swizzle (as R2): logical chunk q of row r stored in slot q^swz(r)
__device__ __forceinline__ int swz(int r) { return (r & 3) ^ ((r >> 2) & 1); }

// async global->LDS, 16B per lane; LDS dest = wave-uniform base + lane*16
__device__ __forceinline__ void gl2lds16(const u16* g, u16* l) {
    __builtin_amdgcn_global_load_lds(
        (const __attribute__((address_space(1))) unsigned int*)g,
        (__attribute__((address_space(3))) unsigned int*)l,
        16, 0, 0);
}

// ---------------------------------------------------------------------------
// init: W(=d_out, incl score slot)=0, Zh/Zl=0 (KP2-padded), emb -> Eh/El,
//       v=1, u=0, norm2=0
// ---------------------------------------------------------------------------
__global__ __launch_bounds__(256) void k_init(float* __restrict__ out,
                                              u16* __restrict__ Zh, u16* __restrict__ Zl,
                                              const float* __restrict__ emb,
                                              u16* __restrict__ Eh, u16* __restrict__ El,
                                              float* __restrict__ v, float* __restrict__ u,
                                              float* __restrict__ norm2) {
    int idx = blockIdx.x * 256 + threadIdx.x;
    int stride = gridDim.x * 256;
    for (int i = idx; i <= B_DIM * K_DIM; i += stride) out[i] = 0.0f;
    unsigned* zh = (unsigned*)Zh;
    unsigned* zl = (unsigned*)Zl;
    for (int i = idx; i < B_DIM * KP2 / 2; i += stride) { zh[i] = 0u; zl[i] = 0u; }
    for (int i = idx; i < B_DIM * D_DIM; i += stride) {
        u16 h, l; split2(emb[i], h, l);
        Eh[i] = h; El[i] = l;
    }
    for (int i = idx; i < K_DIM; i += stride) v[i] = 1.0f;
    for (int i = idx; i < D_DIM; i += stride) u[i] = 0.0f;
    for (int i = idx; i < POWER_ITERS + 1; i += stride) norm2[i] = 0.0f;
}

// ---------------------------------------------------------------------------
// D fp32 [10000,1024] -> Dh/Dl [KB,1024] (rows>=10000 zero)
//                     -> Dth/Dtl [1024,KP2] (cols>=10000 zero)
// grid (320, 32)
// ---------------------------------------------------------------------------
__global__ __launch_bounds__(256) void k_convertD(const float* __restrict__ D,
                                                  u16* __restrict__ Dh,
                                                  u16* __restrict__ Dl,
                                                  u16* __restrict__ Dth,
                                                  u16* __restrict__ Dtl) {
    __shared__ u16 Th[32][33], Tl[32][33];
    int tx = threadIdx.x & 31, ty = threadIdx.x >> 5;
    int k0 = blockIdx.x * 32, d0 = blockIdx.y * 32;
    #pragma unroll
    for (int r = 0; r < 4; ++r) {
        int krow = k0 + ty + r * 8;
        float val = (krow < K_DIM) ? D[(size_t)krow * D_DIM + d0 + tx] : 0.0f;
        u16 h, l; split2(val, h, l);
        if (krow < KB) {
            Dh[(size_t)krow * D_DIM + d0 + tx] = h;
            Dl[(size_t)krow * D_DIM + d0 + tx] = l;
        }
        Th[ty + r * 8][tx] = h;
        Tl[ty + r * 8][tx] = l;
    }
    __syncthreads();
    #pragma unroll
    for (int r = 0; r < 4; ++r) {
        int d = d0 + ty + r * 8;
        int k = k0 + tx;
        Dth[(size_t)d * KP2 + k] = Th[tx][ty + r * 8];
        Dtl[(size_t)d * KP2 + k] = Tl[tx][ty + r * 8];
    }
}

// ---------------------------------------------------------------------------
// power iteration kernels (fp32, unchanged)
// ---------------------------------------------------------------------------
__global__ __launch_bounds__(256) void k_matvec_u(const float* __restrict__ v,
                                                  const float* __restrict__ D,
                                                  float* __restrict__ u) {
    int tid = threadIdx.x;
    int kbase = blockIdx.x * 40;
    float acc0 = 0.f, acc1 = 0.f, acc2 = 0.f, acc3 = 0.f;
    for (int k = kbase; k < kbase + 40; ++k) {
        float vk = v[k];
        const float* row = D + (size_t)k * D_DIM;
        acc0 = fmaf(vk, row[tid], acc0);
        acc1 = fmaf(vk, row[tid + 256], acc1);
        acc2 = fmaf(vk, row[tid + 512], acc2);
        acc3 = fmaf(vk, row[tid + 768], acc3);
    }
    atomicAdd(&u[tid], acc0);
    atomicAdd(&u[tid + 256], acc1);
    atomicAdd(&u[tid + 512], acc2);
    atomicAdd(&u[tid + 768], acc3);
}

__global__ __launch_bounds__(256) void k_matvec_v(const float* __restrict__ u,
                                                  const float* __restrict__ D,
                                                  float* __restrict__ v,
                                                  float* __restrict__ n2,
                                                  int write_v) {
    int wid = blockIdx.x * 4 + (threadIdx.x >> 6);
    int lane = threadIdx.x & 63;
    if (wid >= K_DIM) return;
    const float* row = D + (size_t)wid * D_DIM;
    float acc = 0.f;
    #pragma unroll
    for (int j = 0; j < D_DIM; j += 64) acc = fmaf(u[j + lane], row[j + lane], acc);
    #pragma unroll
    for (int off = 32; off > 0; off >>= 1) acc += __shfl_down(acc, off, 64);
    if (lane == 0) {
        float r = acc * (1.0f / 1024.0f);
        if (write_v) v[wid] = r;
        atomicAdd(n2, r * r);
    }
}

__global__ __launch_bounds__(256) void k_vnormalize(float* __restrict__ v,
                                                    const float* __restrict__ n2,
                                                    float* __restrict__ u) {
    int idx = blockIdx.x * blockDim.x + threadIdx.x;
    float s = 1.0f / (sqrtf(*n2) + 1e-12f);
    if (idx < K_DIM) v[idx] *= s;
    if (idx < D_DIM) u[idx] = 0.0f;
}

__global__ void k_Lfinalize(const float* __restrict__ n2, float* __restrict__ scal) {
    float L = sqrtf(*n2);
    float step = 1.0f / L;
    scal[0] = step;
    scal[1] = step * ALPHA_F;
}

// ---------------------------------------------------------------------------
// G1: Up[ks][128][1024] partial = Z[128, ks*1024 : +1024] @ Dt-slice
// 512 threads = 2 wave-groups; group g does k-half [g*512, g*512+512) (16 steps)
// grid (16 d-tiles, 2 m-tiles, SPLITK)
// ---------------------------------------------------------------------------
__global__ __launch_bounds__(512) void k_g1(const u16* __restrict__ Azh,
                                            const u16* __restrict__ Azl,
                                            const u16* __restrict__ Bth,
                                            const u16* __restrict__ Btl,
                                            float* __restrict__ Up) {
    __shared__ __align__(16) u16 lds[32768];   // 64 KB: [g][buf][chunk4][2048]
    int t = threadIdx.x;
    int g = t >> 8;
    int lt = t & 255;
    int n0 = blockIdx.x * 64;
    int m0 = blockIdx.y * 64;
    int ks = blockIdx.z;
    int kbase = ks * 1024 + g * 512;

    int wg = (t >> 6) & 3;
    int lane = t & 63, quad = lane >> 4, lr = lane & 15;
    int wm = (wg >> 1) * 32, wn = (wg & 1) * 32;

    int r0 = lt >> 2, qs = lt & 3;
    int q = qs ^ swz(r0);
    const u16* gAh = Azh + (size_t)(m0 + r0) * KP2 + kbase + q * 8;
    const u16* gAl = Azl + (size_t)(m0 + r0) * KP2 + kbase + q * 8;
    const u16* gBh = Bth + (size_t)(n0 + r0) * KP2 + kbase + q * 8;
    const u16* gBl = Btl + (size_t)(n0 + r0) * KP2 + kbase + q * 8;

    u16* baseg = lds + g * 16384;
    int wofs = wg * 512;             // wave-uniform dest offset (u16 units)

    int offA[2], offB[2];
    #pragma unroll
    for (int mi = 0; mi < 2; ++mi) { int rr = wm + mi * 16 + lr; offA[mi] = rr * 32 + ((quad ^ swz(rr)) * 8); }
    #pragma unroll
    for (int ni = 0; ni < 2; ++ni) { int rr = wn + ni * 16 + lr; offB[ni] = rr * 32 + ((quad ^ swz(rr)) * 8); }

    f32x4 acc[2][2] = {};

    // prologue stage s=0 into buf 0
    {
        u16* b = baseg;
        gl2lds16(gAh, b + 0 * 2048 + wofs);
        gl2lds16(gAl, b + 1 * 2048 + wofs);
        gl2lds16(gBh, b + 2 * 2048 + wofs);
        gl2lds16(gBl, b + 3 * 2048 + wofs);
    }
    for (int s = 0; s < 16; ++s) {
        __syncthreads();    // drains async loads for buf s&1
        if (s + 1 < 16) {
            u16* b = baseg + ((s + 1) & 1) * 8192;
            int c = (s + 1) * 32;
            gl2lds16(gAh + c, b + 0 * 2048 + wofs);
            gl2lds16(gAl + c, b + 1 * 2048 + wofs);
            gl2lds16(gBh + c, b + 2 * 2048 + wofs);
            gl2lds16(gBl + c, b + 3 * 2048 + wofs);
        }
        u16* b = baseg + (s & 1) * 8192;
        bf16x8 aH[2], aL[2], bH[2], bL[2];
        #pragma unroll
        for (int mi = 0; mi < 2; ++mi) {
            aH[mi] = *(const bf16x8*)&b[0 * 2048 + offA[mi]];
            aL[mi] = *(const bf16x8*)&b[1 * 2048 + offA[mi]];
        }
        #pragma unroll
        for (int ni = 0; ni < 2; ++ni) {
            bH[ni] = *(const bf16x8*)&b[2 * 2048 + offB[ni]];
            bL[ni] = *(const bf16x8*)&b[3 * 2048 + offB[ni]];
        }
        #pragma unroll
        for (int mi = 0; mi < 2; ++mi)
            #pragma unroll
            for (int ni = 0; ni < 2; ++ni) {
                acc[mi][ni] = MFMA(aL[mi], bH[ni], acc[mi][ni], 0, 0, 0);
                acc[mi][ni] = MFMA(aH[mi], bL[ni], acc[mi][ni], 0, 0, 0);
                acc[mi][ni] = MFMA(aH[mi], bH[ni], acc[mi][ni], 0, 0, 0);
            }
    }
    // cross-group reduce in LDS, then group 0 stores partial tile
    __syncthreads();
    float* Cs = (float*)lds;     // [64][66]
    if (g == 1) {
        #pragma unroll
        for (int mi = 0; mi < 2; ++mi)
            #pragma unroll
            for (int ni = 0; ni < 2; ++ni)
                #pragma unroll
                for (int r = 0; r < 4; ++r)
                    Cs[(wm + mi * 16 + quad * 4 + r) * 66 + wn + ni * 16 + lr] = acc[mi][ni][r];
    }
    __syncthreads();
    if (g == 0) {
        float* o = Up + (size_t)ks * (B_DIM * D_DIM);
        #pragma unroll
        for (int mi = 0; mi < 2; ++mi)
            #pragma unroll
            for (int ni = 0; ni < 2; ++ni) {
                int col = wn + ni * 16 + lr;
                #pragma unroll
                for (int r = 0; r < 4; ++r) {
                    int row = wm + mi * 16 + quad * 4 + r;
                    o[(size_t)(m0 + row) * D_DIM + n0 + col] = acc[mi][ni][r] + Cs[row * 66 + col];
                }
            }
    }
}

// ---------------------------------------------------------------------------
// reduce Up over SPLITK -> Uh/Ul (split bf16)
// ---------------------------------------------------------------------------
__global__ __launch_bounds__(256) void k_reduceU(const float* __restrict__ Up,
                                                 u16* __restrict__ Uh,
                                                 u16* __restrict__ Ul) {
    int base = (blockIdx.x * 256 + threadIdx.x) * 8;    // grid 64 -> 131072 elems
    float4 s0 = {0, 0, 0, 0}, s1 = {0, 0, 0, 0};
    #pragma unroll
    for (int s = 0; s < SPLITK; ++s) {
        const float* p = Up + (size_t)s * (B_DIM * D_DIM) + base;
        float4 a = *(const float4*)p;
        float4 b = *(const float4*)(p + 4);
        s0.x += a.x; s0.y += a.y; s0.z += a.z; s0.w += a.w;
        s1.x += b.x; s1.y += b.y; s1.z += b.z; s1.w += b.w;
    }
    float vbuf[8] = {s0.x, s0.y, s0.z, s0.w, s1.x, s1.y, s1.z, s1.w};
    union { u16 us[8]; int4 v; } h, l;
    #pragma unroll
    for (int qq = 0; qq < 8; ++qq) split2(vbuf[qq], h.us[qq], l.us[qq]);
    *(int4*)&Uh[base] = h.v;
    *(int4*)&Ul[base] = l.v;
}

// ---------------------------------------------------------------------------
// G2: acc[128,KB] = A[128,1024] @ Dh^T ; 512 thr, 2 wave-groups over K halves.
// mode 0: R = acc/n   mode 1: fused FISTA prox (writes W, Zh/Zl)
// grid (157, 2)
// ---------------------------------------------------------------------------
__global__ __launch_bounds__(512) void k_g2(const u16* __restrict__ Ahg,
                                            const u16* __restrict__ Alg,
                                            const u16* __restrict__ Bhg,
                                            const u16* __restrict__ Blg,
                                            float* __restrict__ R,
                                            float* __restrict__ W,
                                            u16* __restrict__ Zh, u16* __restrict__ Zl,
                                            const float* __restrict__ scal,
                                            float mom, int mode, int writeW) {
    __shared__ __align__(16) u16 lds[32768];
    int t = threadIdx.x;
    int g = t >> 8;
    int lt = t & 255;
    int n0 = blockIdx.x * 64;     // concept tile
    int i0 = blockIdx.y * 64;     // batch tile
    int kbase = g * 512;

    int wg = (t >> 6) & 3;
    int lane = t & 63, quad = lane >> 4, lr = lane & 15;
    int wm = (wg >> 1) * 32, wn = (wg & 1) * 32;

    int r0 = lt >> 2, qs = lt & 3;
    int q = qs ^ swz(r0);
    const u16* gAh = Ahg + (size_t)(i0 + r0) * D_DIM + kbase + q * 8;
    const u16* gAl = Alg + (size_t)(i0 + r0) * D_DIM + kbase + q * 8;
    const u16* gBh = Bhg + (size_t)(n0 + r0) * D_DIM + kbase + q * 8;
    const u16* gBl = Blg + (size_t)(n0 + r0) * D_DIM + kbase + q * 8;

    u16* baseg = lds + g * 16384;
    int wofs = wg * 512;

    int offA[2], offB[2];
    #pragma unroll
    for (int mi = 0; mi < 2; ++mi) { int rr = wm + mi * 16 + lr; offA[mi] = rr * 32 + ((quad ^ swz(rr)) * 8); }
    #pragma unroll
    for (int ni = 0; ni < 2; ++ni) { int rr = wn + ni * 16 + lr; offB[ni] = rr * 32 + ((quad ^ swz(rr)) * 8); }

    f32x4 acc[2][2] = {};

    {
        u16* b = baseg;
        gl2lds16(gAh, b + 0 * 2048 + wofs);
        gl2lds16(gAl, b + 1 * 2048 + wofs);
        gl2lds16(gBh, b + 2 * 2048 + wofs);
        gl2lds16(gBl, b + 3 * 2048 + wofs);
    }
    for (int s = 0; s < 16; ++s) {
        __syncthreads();
        if (s + 1 < 16) {
            u16* b = baseg + ((s + 1) & 1) * 8192;
            int c = (s + 1) * 32;
            gl2lds16(gAh + c, b + 0 * 2048 + wofs);
            gl2lds16(gAl + c, b + 1 * 2048 + wofs);
            gl2lds16(gBh + c, b + 2 * 2048 + wofs);
            gl2lds16(gBl + c, b + 3 * 2048 + wofs);
        }
        u16* b = baseg + (s & 1) * 8192;
        bf16x8 aH[2], aL[2], bH[2], bL[2];
        #pragma unroll
        for (int mi = 0; mi < 2; ++mi) {
            aH[mi] = *(const bf16x8*)&b[0 * 2048 + offA[mi]];
            aL[mi] = *(const bf16x8*)&b[1 * 2048 + offA[mi]];
        }
        #pragma unroll
        for (int ni = 0; ni < 2; ++ni) {
            bH[ni] = *(const bf16x8*)&b[2 * 2048 + offB[ni]];
            bL[ni] = *(const bf16x8*)&b[3 * 2048 + offB[ni]];
        }
        #pragma unroll
        for (int mi = 0; mi < 2; ++mi)
            #pragma unroll
            for (int ni = 0; ni < 2; ++ni) {
                acc[mi][ni] = MFMA(aL[mi], bH[ni], acc[mi][ni], 0, 0, 0);
                acc[mi][ni] = MFMA(aH[mi], bL[ni], acc[mi][ni], 0, 0, 0);
                acc[mi][ni] = MFMA(aH[mi], bH[ni], acc[mi][ni], 0, 0, 0);
            }
    }
    __syncthreads();
    float* Cs = (float*)lds;     // [64][66]
    if (g == 1) {
        #pragma unroll
        for (int mi = 0; mi < 2; ++mi)
            #pragma unroll
            for (int ni = 0; ni < 2; ++ni)
                #pragma unroll
                for (int r = 0; r < 4; ++r)
                    Cs[(wm + mi * 16 + quad * 4 + r) * 66 + wn + ni * 16 + lr] = acc[mi][ni][r];
    }
    __syncthreads();
    if (g == 0) {
        const float invN = 1.0f / 1024.0f;
        if (mode == 0) {
            #pragma unroll
            for (int mi = 0; mi < 2; ++mi)
                #pragma unroll
                for (int ni = 0; ni < 2; ++ni) {
                    int col = wn + ni * 16 + lr;
                    int k = n0 + col;
                    #pragma unroll
                    for (int r = 0; r < 4; ++r) {
                        int row = wm + mi * 16 + quad * 4 + r;
                        float a = acc[mi][ni][r] + Cs[row * 66 + col];
                        R[(size_t)(i0 + row) * KB + k] = a * invN;
                    }
                }
        } else {
            float step = scal[0], th = scal[1];
            #pragma unroll
            for (int mi = 0; mi < 2; ++mi)
                #pragma unroll
                for (int ni = 0; ni < 2; ++ni) {
                    int col = wn + ni * 16 + lr;
                    int k = n0 + col;
                    #pragma unroll
                    for (int r = 0; r < 4; ++r) {
                        int row = wm + mi * 16 + quad * 4 + r;
                        int i = i0 + row;
                        float a = acc[mi][ni][r] + Cs[row * 66 + col];
                        float gg = a * invN - R[(size_t)i * KB + k];
                        size_t iz = (size_t)i * KP2 + k;
                        float z = bf2f(Zh[iz]) + bf2f(Zl[iz]);
                        float wold = (k < K_DIM) ? W[(size_t)i * K_DIM + k] : 0.0f;
                        float wnew = fmaxf(z - step * gg - th, 0.0f);
                        float zn = wnew + mom * (wnew - wold);
                        if (k < K_DIM) W[(size_t)i * K_DIM + k] = wnew;
                        u16 h, l;
                        if (writeW) split2(wnew, h, l);
                        else        split2(zn, h, l);
                        Zh[iz] = h;
                        Zl[iz] = l;
                    }
                }
        }
    }
}

// ---------------------------------------------------------------------------
// score = sum_i <recon_i, emb_i> / (||recon_i|| + 1e-12); recon from split U
// ---------------------------------------------------------------------------
__global__ __launch_bounds__(256) void k_score(const u16* __restrict__ Uh,
                                               const u16* __restrict__ Ul,
                                               const float* __restrict__ emb,
                                               float* __restrict__ score) {
    int wid = blockIdx.x * 4 + (threadIdx.x >> 6);
    int lane = threadIdx.x & 63;
    if (wid >= B_DIM) return;
    float rr = 0.f, re = 0.f;
    #pragma unroll
    for (int j = 0; j < D_DIM; j += 64) {
        int idx = wid * D_DIM + j + lane;
        float x = bf2f(Uh[idx]) + bf2f(Ul[idx]);
        rr = fmaf(x, x, rr);
        re = fmaf(x, emb[idx], re);
    }
    #pragma unroll
    for (int off = 32; off > 0; off >>= 1) {
        rr += __shfl_down(rr, off, 64);
        re += __shfl_down(re, off, 64);
    }
    if (lane == 0) atomicAdd(score, re / (sqrtf(rr) + 1e-12f));
}

// ---------------------------------------------------------------------------
extern "C" void kernel_launch(void* const* d_in, const int* in_sizes, int n_in,
                              void* d_out, int out_size, void* d_ws, size_t ws_size,
                              hipStream_t stream) {
    const float* emb = (const float*)d_in[0];   // [128,1024]
    const float* Dm  = (const float*)d_in[1];   // [10000,1024]
    float* out = (float*)d_out;
    float* W = out;                             // [128][10000] lives in d_out

    size_t off = 0;
    auto carve = [&](size_t bytes) -> void* {
        void* r = (char*)d_ws + off;
        off += (bytes + 255) & ~(size_t)255;
        return r;
    };
    float* R     = (float*)carve((size_t)B_DIM * KB * 4);               // 5.15 MB
    float* Up    = (float*)carve((size_t)SPLITK * B_DIM * D_DIM * 4);   // 5.24 MB
    u16*   Zh    = (u16*)carve((size_t)B_DIM * KP2 * 2);                // 2.62 MB
    u16*   Zl    = (u16*)carve((size_t)B_DIM * KP2 * 2);
    u16*   Uh    = (u16*)carve((size_t)B_DIM * D_DIM * 2);              // 0.26 MB
    u16*   Ul    = (u16*)carve((size_t)B_DIM * D_DIM * 2);
    float* v     = (float*)carve(K_DIM * 4);
    float* u     = (float*)carve(D_DIM * 4);
    float* norm2 = (float*)carve((POWER_ITERS + 1) * 4);
    float* scal  = (float*)carve(2 * 4);
    u16* Dh  = (u16*)carve((size_t)KB * D_DIM * 2);                     // 20.6 MB
    u16* Dl  = (u16*)carve((size_t)KB * D_DIM * 2);
    u16* Dth = (u16*)carve((size_t)D_DIM * KP2 * 2);                    // 21.0 MB
    u16* Dtl = (u16*)carve((size_t)D_DIM * KP2 * 2);

    k_init<<<512, 256, 0, stream>>>(out, Zh, Zl, emb, Uh, Ul, v, u, norm2);
    k_convertD<<<dim3(320, 32), 256, 0, stream>>>(Dm, Dh, Dl, Dth, Dtl);

    // ---- power iteration for Lipschitz constant (fp32) ----
    for (int it = 0; it < POWER_ITERS; ++it) {
        k_matvec_u<<<250, 256, 0, stream>>>(v, Dm, u);
        k_matvec_v<<<2500, 256, 0, stream>>>(u, Dm, v, norm2 + it, 1);
        k_vnormalize<<<40, 256, 0, stream>>>(v, norm2 + it, u);
    }
    k_matvec_u<<<250, 256, 0, stream>>>(v, Dm, u);
    k_matvec_v<<<2500, 256, 0, stream>>>(u, Dm, nullptr, norm2 + POWER_ITERS, 0);
    k_Lfinalize<<<1, 1, 0, stream>>>(norm2 + POWER_ITERS, scal);

    // ---- R = Y @ D^T / n (mode 0; A = split emb staged in Uh/Ul) ----
    k_g2<<<dim3(157, 2), 512, 0, stream>>>(Uh, Ul, Dh, Dl, R, W, Zh, Zl,
                                           scal, 0.0f, 0, 0);

    // ---- FISTA ----
    double t = 1.0;
    for (int it = 0; it < N_ITERS; ++it) {
        double tn = 0.5 * (1.0 + sqrt(1.0 + 4.0 * t * t));
        float mom = (float)((t - 1.0) / tn);
        t = tn;
        k_g1<<<dim3(16, 2, SPLITK), 512, 0, stream>>>(Zh, Zl, Dth, Dtl, Up);
        k_reduceU<<<64, 256, 0, stream>>>(Up, Uh, Ul);
        k_g2<<<dim3(157, 2), 512, 0, stream>>>(Uh, Ul, Dh, Dl, R, W, Zh, Zl,
                                               scal, mom, 1,
                                               (it == N_ITERS - 1) ? 1 : 0);
    }

    // ---- epilogue: recon = W@D (Zh/Zl hold split W), then score ----
    k_g1<<<dim3(16, 2, SPLITK), 512, 0, stream>>>(Zh, Zl, Dth, Dtl, Up);
    k_reduceU<<<64, 256, 0, stream>>>(Up, Uh, Ul);
    k_score<<<32, 256, 0, stream>>>(Uh, Ul, emb, out + (size_t)B_DIM * K_DIM);
}